// Round 2
// 1817.053 us; speedup vs baseline: 1.4252x; 1.4252x over previous
//
#include <hip/hip_runtime.h>

typedef unsigned short u16;
typedef __bf16 bf16x8 __attribute__((ext_vector_type(8)));
typedef float f32x4 __attribute__((ext_vector_type(4)));

#define DEV __device__ __forceinline__

static constexpr int Bb = 4, Ss = 2048, Dd = 2048, Hh = 16, DK = 128;

DEV u16 f2bf(float f){
  unsigned u = __builtin_bit_cast(unsigned, f);
  return (u16)((u + 0x7fffu + ((u >> 16) & 1u)) >> 16);
}

DEV void async16(const void* g, void* l){
  __builtin_amdgcn_global_load_lds(
      (const __attribute__((address_space(1))) unsigned int*)(unsigned long long)g,
      (__attribute__((address_space(3))) unsigned int*)(unsigned int)(unsigned long long)l,
      16, 0, 0);
}

DEV bf16x8 ldsv(const u16* p){ return *(const bf16x8*)p; }

// swizzled read of a [128][128] bf16 tile staged with pre-swizzled source.
// row in [0,128), cb = byte column (multiple of 16). byte ^= (row&7)<<4.
DEV bf16x8 ldswz(const u16* base, int row, int cb){
  return *(const bf16x8*)((const char*)base + row * 256 + (cb ^ ((row & 7) << 4)));
}

// ---------------- prep kernels ----------------
__global__ __launch_bounds__(256) void cvt_kernel(const float* __restrict__ s,
                                                  u16* __restrict__ d, int n4){
  int i = blockIdx.x * 256 + threadIdx.x;
  if (i < n4){
    float4 v = ((const float4*)s)[i];
    ushort4 o;
    o.x = f2bf(v.x); o.y = f2bf(v.y); o.z = f2bf(v.z); o.w = f2bf(v.w);
    ((ushort4*)d)[i] = o;
  }
}

__global__ __launch_bounds__(256) void rope_kernel(float* __restrict__ rf){
  int i = blockIdx.x * 256 + threadIdx.x;   // [2048][128]
  int s = i >> 7, dk = i & 127;
  float freq = __expf(-(float)(dk & ~1) * 0.0719557841560639344f); // ln(1e4)/128
  float a = (float)s * freq;
  rf[i] = cosf(a) + sinf(a);
}

__global__ __launch_bounds__(256) void bias_kernel(const float* __restrict__ mask,
                                                   float* __restrict__ kb, int n){
  int i = blockIdx.x * 256 + threadIdx.x;
  if (i < n) kb[i] = (1.0f - mask[i]) * (-1e9f);
}

// ---------------- 128x128 bf16 GEMM (C = A * B^T), m97 structure ----------------
DEV void gemm_mainloop(const u16* __restrict__ A, const u16* __restrict__ B,
                       int m0, int n0, int K, u16* As, u16* Bs,
                       int wave, int lane, f32x4 acc[4][4]){
  const int l15 = lane & 15, l4 = lane >> 4;
  const int wm = (wave >> 1) * 64, wn = (wave & 1) * 64;
  for (int k0 = 0; k0 < K; k0 += 32){
    __syncthreads();
#pragma unroll
    for (int i = 0; i < 2; i++){
      const int c = i * 256 + wave * 64 + lane;
      const int r = c >> 2, ci = (c & 3) << 3;
      async16(A + (size_t)(m0 + r) * K + k0 + ci, As + c * 8);
      async16(B + (size_t)(n0 + r) * K + k0 + ci, Bs + c * 8);
    }
    __syncthreads();
    bf16x8 af[4], bv[4];
#pragma unroll
    for (int mi = 0; mi < 4; mi++) af[mi] = ldsv(As + (wm + mi * 16 + l15) * 32 + l4 * 8);
#pragma unroll
    for (int ni = 0; ni < 4; ni++) bv[ni] = ldsv(Bs + (wn + ni * 16 + l15) * 32 + l4 * 8);
#pragma unroll
    for (int mi = 0; mi < 4; mi++)
#pragma unroll
      for (int ni = 0; ni < 4; ni++)
        acc[mi][ni] = __builtin_amdgcn_mfma_f32_16x16x32_bf16(af[mi], bv[ni], acc[mi][ni], 0, 0, 0);
  }
}

// qkv = x @ w_qkv^T, epilogue: rope on q,k + scatter to [B,H,S,DK] bf16.
// V is written TRANSPOSED: [B,H,DK,S] so attn can stage V^T linearly.
__global__ __launch_bounds__(256) void gemm_qkv_kernel(
    const u16* __restrict__ A, const u16* __restrict__ Bw, const float* __restrict__ rf,
    u16* __restrict__ q_out, u16* __restrict__ k_out, u16* __restrict__ vt_out){
  __shared__ u16 As[128 * 32], Bs[128 * 32];
  const int tid = threadIdx.x, wave = tid >> 6, lane = tid & 63;
  const int l15 = lane & 15, l4 = lane >> 4;
  const int m0 = blockIdx.y * 128, n0 = blockIdx.x * 128;
  const int wm = (wave >> 1) * 64, wn = (wave & 1) * 64;
  f32x4 acc[4][4];
  const f32x4 z = {0.f, 0.f, 0.f, 0.f};
#pragma unroll
  for (int mi = 0; mi < 4; mi++)
#pragma unroll
    for (int ni = 0; ni < 4; ni++) acc[mi][ni] = z;

  gemm_mainloop(A, Bw, m0, n0, 2048, As, Bs, wave, lane, acc);

  const int which = n0 >> 11, h = (n0 >> 7) & 15;
  if (which == 2){
    // V^T write: [b,h,dk,s]; r=0..3 are 4 consecutive s -> ushort4 store.
#pragma unroll
    for (int mi = 0; mi < 4; mi++){
      int mbase = m0 + wm + mi * 16 + l4 * 4;
      int b = mbase >> 11, s = mbase & 2047;
#pragma unroll
      for (int ni = 0; ni < 4; ni++){
        int dk = wn + ni * 16 + l15;
        ushort4 o;
        o.x = f2bf(acc[mi][ni][0]); o.y = f2bf(acc[mi][ni][1]);
        o.z = f2bf(acc[mi][ni][2]); o.w = f2bf(acc[mi][ni][3]);
        *(ushort4*)(vt_out + ((size_t)(b * Hh + h) * DK + dk) * Ss + s) = o;
      }
    }
  } else {
    u16* dst = which == 0 ? q_out : k_out;
#pragma unroll
    for (int mi = 0; mi < 4; mi++)
#pragma unroll
      for (int r = 0; r < 4; r++){
        int m = m0 + wm + mi * 16 + l4 * 4 + r;
        int b = m >> 11, s = m & 2047;
        size_t rowbase = ((size_t)(b * Hh + h) * Ss + s) * DK;
#pragma unroll
        for (int ni = 0; ni < 4; ni++){
          int dk = wn + ni * 16 + l15;
          float v = acc[mi][ni][r] * rf[s * DK + dk];
          dst[rowbase + dk] = f2bf(v);
        }
      }
  }
}

// output = o @ w_o^T  (fp32 epilogue into d_out)
__global__ __launch_bounds__(256) void gemm_out_kernel(
    const u16* __restrict__ A, const u16* __restrict__ Bw, float* __restrict__ out){
  __shared__ u16 As[128 * 32], Bs[128 * 32];
  const int tid = threadIdx.x, wave = tid >> 6, lane = tid & 63;
  const int l15 = lane & 15, l4 = lane >> 4;
  const int m0 = blockIdx.y * 128, n0 = blockIdx.x * 128;
  const int wm = (wave >> 1) * 64, wn = (wave & 1) * 64;
  f32x4 acc[4][4];
  const f32x4 z = {0.f, 0.f, 0.f, 0.f};
#pragma unroll
  for (int mi = 0; mi < 4; mi++)
#pragma unroll
    for (int ni = 0; ni < 4; ni++) acc[mi][ni] = z;

  gemm_mainloop(A, Bw, m0, n0, 2048, As, Bs, wave, lane, acc);

#pragma unroll
  for (int mi = 0; mi < 4; mi++)
#pragma unroll
    for (int r = 0; r < 4; r++){
      int m = m0 + wm + mi * 16 + l4 * 4 + r;
#pragma unroll
      for (int ni = 0; ni < 4; ni++)
        out[(size_t)m * Dd + n0 + wn + ni * 16 + l15] = acc[mi][ni][r];
    }
}

// ---------------- attention ----------------
// 1D grid 2048. XCD-clustered (each XCD owns 8 bh -> K/V L2-resident) +
// heavy-first (LPT) causal scheduling. block 256 = 4 waves (2x2 over [64q x 128k]).
__global__ __launch_bounds__(256) void attn_kernel(
    const u16* __restrict__ qg, const u16* __restrict__ kg, const u16* __restrict__ vtg,
    const float* __restrict__ kbias, float* __restrict__ attn, u16* __restrict__ obuf){
  __shared__ u16 KV[128 * 128];     // swizzled K tile, then swizzled V^T tile
  __shared__ u16 Ps[64 * 136];      // P tile in A-operand layout (272B stride: read-conflict-free)
  __shared__ float m_s[64], l_s[64], a_s[64], red0[64], red1[64];

  const int tid = threadIdx.x, wave = tid >> 6, lane = tid & 63;
  const int l15 = lane & 15, l4 = lane >> 4;
  // bid -> (xcd, idx); each XCD processes bh = xcd*8..xcd*8+7, heavy q-tiles first
  const int bid = blockIdx.x;
  const int virt = (bid & 7) * 256 + (bid >> 3);
  const int bh = virt >> 5, b = bh >> 4, h = bh & 15;
  const int q0 = (31 - (virt & 31)) << 6;
  const int wq = (wave >> 1) * 32, wk = (wave & 1) * 64;

  const size_t bhoff = (size_t)bh * Ss * DK;
  const u16* qp = qg + bhoff;
  const u16* kp = kg + bhoff;
  const u16* vp = vtg + bhoff;     // [dk][s]

  // Q fragments in registers: rows q0+wq..+31, full K=128
  bf16x8 qf[2][4];
#pragma unroll
  for (int mi = 0; mi < 2; mi++)
#pragma unroll
    for (int ks = 0; ks < 4; ks++)
      qf[mi][ks] = ldsv(qp + (size_t)(q0 + wq + mi * 16 + l15) * DK + ks * 32 + l4 * 8);

  if (tid < 64){ m_s[tid] = -1e30f; l_s[tid] = 0.f; }

  const int ntiles = (q0 >> 7) + 1;
  const float scale = 0.08838834764831845f;   // 1/sqrt(128)
  const f32x4 z = {0.f, 0.f, 0.f, 0.f};

  // ---------- pass 1: row max / sum ----------
  for (int t = 0; t < ntiles; t++){
    const int j0 = t << 7;
    __syncthreads();
    // stage K tile, pre-swizzled source (dest linear for global_load_lds)
#pragma unroll
    for (int i = 0; i < 8; i++){
      int c = i * 256 + tid;
      int r = c >> 4, cb = (c & 15) << 4;
      int scb = cb ^ ((r & 7) << 4);
      async16(kp + (size_t)(j0 + r) * DK + (scb >> 1), (char*)KV + (size_t)c * 16);
    }
    __syncthreads();
    f32x4 sacc[2][4];
#pragma unroll
    for (int mi = 0; mi < 2; mi++)
#pragma unroll
      for (int ni = 0; ni < 4; ni++) sacc[mi][ni] = z;
    __builtin_amdgcn_s_setprio(1);
#pragma unroll
    for (int ks = 0; ks < 4; ks++){
      bf16x8 kf[4];
#pragma unroll
      for (int ni = 0; ni < 4; ni++) kf[ni] = ldswz(KV, wk + ni * 16 + l15, ks * 64 + l4 * 16);
#pragma unroll
      for (int mi = 0; mi < 2; mi++)
#pragma unroll
        for (int ni = 0; ni < 4; ni++)
          sacc[mi][ni] = __builtin_amdgcn_mfma_f32_16x16x32_bf16(qf[mi][ks], kf[ni], sacc[mi][ni], 0, 0, 0);
    }
    __builtin_amdgcn_s_setprio(0);
    float kb4[4];
#pragma unroll
    for (int ni = 0; ni < 4; ni++) kb4[ni] = kbias[b * Ss + j0 + wk + ni * 16 + l15];

    float rmx[2][4];
#pragma unroll
    for (int mi = 0; mi < 2; mi++)
#pragma unroll
      for (int r = 0; r < 4; r++) rmx[mi][r] = -3e38f;
#pragma unroll
    for (int mi = 0; mi < 2; mi++)
#pragma unroll
      for (int ni = 0; ni < 4; ni++)
#pragma unroll
        for (int r = 0; r < 4; r++){
          int qi = q0 + wq + mi * 16 + l4 * 4 + r;
          int kj = j0 + wk + ni * 16 + l15;
          float sv = sacc[mi][ni][r] * scale + kb4[ni];
          sv = (kj > qi) ? -1e9f : sv;
          sacc[mi][ni][r] = sv;
          rmx[mi][r] = fmaxf(rmx[mi][r], sv);
        }
#pragma unroll
    for (int d = 1; d < 16; d <<= 1)
#pragma unroll
      for (int mi = 0; mi < 2; mi++)
#pragma unroll
        for (int r = 0; r < 4; r++) rmx[mi][r] = fmaxf(rmx[mi][r], __shfl_xor(rmx[mi][r], d, 64));
    if (l15 == 0){
      float* red = (wave & 1) ? red1 : red0;
#pragma unroll
      for (int mi = 0; mi < 2; mi++)
#pragma unroll
        for (int r = 0; r < 4; r++) red[wq + mi * 16 + l4 * 4 + r] = rmx[mi][r];
    }
    __syncthreads();
    if (tid < 64){
      float mo = m_s[tid];
      float mn = fmaxf(mo, fmaxf(red0[tid], red1[tid]));
      m_s[tid] = mn;
      a_s[tid] = __expf(mo - mn);
    }
    __syncthreads();
    float es[2][4];
#pragma unroll
    for (int mi = 0; mi < 2; mi++)
#pragma unroll
      for (int r = 0; r < 4; r++){
        float mn = m_s[wq + mi * 16 + l4 * 4 + r];
        float e = 0.f;
#pragma unroll
        for (int ni = 0; ni < 4; ni++) e += __expf(sacc[mi][ni][r] - mn);
        es[mi][r] = e;
      }
#pragma unroll
    for (int d = 1; d < 16; d <<= 1)
#pragma unroll
      for (int mi = 0; mi < 2; mi++)
#pragma unroll
        for (int r = 0; r < 4; r++) es[mi][r] += __shfl_xor(es[mi][r], d, 64);
    if (l15 == 0){
      float* red = (wave & 1) ? red1 : red0;
#pragma unroll
      for (int mi = 0; mi < 2; mi++)
#pragma unroll
        for (int r = 0; r < 4; r++) red[wq + mi * 16 + l4 * 4 + r] = es[mi][r];
    }
    __syncthreads();
    if (tid < 64) l_s[tid] = l_s[tid] * a_s[tid] + red0[tid] + red1[tid];
  }
  __syncthreads();
  if (tid < 64) l_s[tid] = 1.0f / l_s[tid];

  // ---------- pass 2: write attn + accumulate O ----------
  f32x4 oacc[2][4];
#pragma unroll
  for (int mi = 0; mi < 2; mi++)
#pragma unroll
    for (int ni = 0; ni < 4; ni++) oacc[mi][ni] = z;

  for (int t = 0; t < ntiles; t++){
    const int j0 = t << 7;
    __syncthreads();   // prev tile's PV reads of KV/Ps done
#pragma unroll
    for (int i = 0; i < 8; i++){
      int c = i * 256 + tid;
      int r = c >> 4, cb = (c & 15) << 4;
      int scb = cb ^ ((r & 7) << 4);
      async16(kp + (size_t)(j0 + r) * DK + (scb >> 1), (char*)KV + (size_t)c * 16);
    }
    __syncthreads();
    f32x4 sacc[2][4];
#pragma unroll
    for (int mi = 0; mi < 2; mi++)
#pragma unroll
      for (int ni = 0; ni < 4; ni++) sacc[mi][ni] = z;
    __builtin_amdgcn_s_setprio(1);
#pragma unroll
    for (int ks = 0; ks < 4; ks++){
      bf16x8 kf[4];
#pragma unroll
      for (int ni = 0; ni < 4; ni++) kf[ni] = ldswz(KV, wk + ni * 16 + l15, ks * 64 + l4 * 16);
#pragma unroll
      for (int mi = 0; mi < 2; mi++)
#pragma unroll
        for (int ni = 0; ni < 4; ni++)
          sacc[mi][ni] = __builtin_amdgcn_mfma_f32_16x16x32_bf16(qf[mi][ks], kf[ni], sacc[mi][ni], 0, 0, 0);
    }
    __builtin_amdgcn_s_setprio(0);
    float kb4[4];
#pragma unroll
    for (int ni = 0; ni < 4; ni++) kb4[ni] = kbias[b * Ss + j0 + wk + ni * 16 + l15];
#pragma unroll
    for (int mi = 0; mi < 2; mi++)
#pragma unroll
      for (int r = 0; r < 4; r++){
        int row = wq + mi * 16 + l4 * 4 + r;
        int qi = q0 + row;
        float mn = m_s[row], il = l_s[row];
        size_t abase = ((size_t)bh * Ss + qi) * Ss + j0 + wk;
#pragma unroll
        for (int ni = 0; ni < 4; ni++){
          int kj = j0 + wk + ni * 16 + l15;
          float sv = sacc[mi][ni][r] * scale + kb4[ni];
          sv = (kj > qi) ? -1e9f : sv;
          float p = __expf(sv - mn) * il;
          attn[abase + ni * 16 + l15] = p;
          sacc[mi][ni][r] = p;
        }
      }
    __syncthreads();   // all K-frag reads of KV done
    // stage V^T tile (swizzled source, async) — overlaps with Ps writes below
#pragma unroll
    for (int i = 0; i < 8; i++){
      int c = i * 256 + tid;
      int r = c >> 4, cb = (c & 15) << 4;
      int scb = cb ^ ((r & 7) << 4);
      async16(vp + (size_t)r * Ss + j0 + (scb >> 1), (char*)KV + (size_t)c * 16);
    }
    // write P (bf16, A-operand layout)
#pragma unroll
    for (int mi = 0; mi < 2; mi++)
#pragma unroll
      for (int ni = 0; ni < 4; ni++)
#pragma unroll
        for (int r = 0; r < 4; r++){
          int row = wq + mi * 16 + l4 * 4 + r;
          Ps[row * 136 + wk + ni * 16 + l15] = f2bf(sacc[mi][ni][r]);
        }
    __syncthreads();
    __builtin_amdgcn_s_setprio(1);
#pragma unroll
    for (int ks = 0; ks < 4; ks++){
      bf16x8 pf[2], vf[4];
#pragma unroll
      for (int mi = 0; mi < 2; mi++) pf[mi] = ldsv(Ps + (wq + mi * 16 + l15) * 136 + ks * 32 + l4 * 8);
#pragma unroll
      for (int ni = 0; ni < 4; ni++) vf[ni] = ldswz(KV, wk + ni * 16 + l15, ks * 64 + l4 * 16);
#pragma unroll
      for (int mi = 0; mi < 2; mi++)
#pragma unroll
        for (int ni = 0; ni < 4; ni++)
          oacc[mi][ni] = __builtin_amdgcn_mfma_f32_16x16x32_bf16(pf[mi], vf[ni], oacc[mi][ni], 0, 0, 0);
    }
    __builtin_amdgcn_s_setprio(0);
  }

  // epilogue: O -> obuf [B,S,H*DK] bf16
#pragma unroll
  for (int mi = 0; mi < 2; mi++)
#pragma unroll
    for (int r = 0; r < 4; r++){
      int row = wq + mi * 16 + l4 * 4 + r;
      int s = q0 + row;
#pragma unroll
      for (int ni = 0; ni < 4; ni++){
        int dk = wk + ni * 16 + l15;
        obuf[(size_t)(b * Ss + s) * Dd + h * DK + dk] = f2bf(oacc[mi][ni][r]);
      }
    }

  // zero-fill attn cols [ntiles*128, 2048) for rows q0..q0+63
  int c0 = ntiles << 7;
  if (c0 < Ss){
    int nf4 = (Ss - c0) >> 2;
    size_t base = ((size_t)bh * Ss + q0) * Ss;
    for (int idx = tid; idx < nf4 * 64; idx += 256){
      int rr = idx / nf4, cc = idx - rr * nf4;
      *(float4*)(attn + base + (size_t)rr * Ss + c0 + cc * 4) = make_float4(0.f, 0.f, 0.f, 0.f);
    }
  }
}

// ---------------- launch ----------------
extern "C" void kernel_launch(void* const* d_in, const int* in_sizes, int n_in,
                              void* d_out, int out_size, void* d_ws, size_t ws_size,
                              hipStream_t stream){
  const float* x     = (const float*)d_in[0];
  const float* amask = (const float*)d_in[1];
  const float* wqkv  = (const float*)d_in[2];
  const float* wo    = (const float*)d_in[3];

  float* out  = (float*)d_out;                       // [4,2048,2048]
  float* attn = out + (size_t)Bb * Ss * Dd;          // [4,16,2048,2048]

  char* ws = (char*)d_ws;
  u16*  xb    = (u16*)(ws + 0);                      // 33.5 MB (reused as obuf)
  u16*  wqkvb = (u16*)(ws + 33554432ull);            // 25.2 MB
  u16*  wob   = (u16*)(ws + 58720256ull);            // 8.4 MB
  u16*  qb    = (u16*)(ws + 67108864ull);            // 33.5 MB
  u16*  kb    = (u16*)(ws + 100663296ull);           // 33.5 MB
  u16*  vtb   = (u16*)(ws + 134217728ull);           // 33.5 MB  (V transposed [B,H,DK,S])
  float* rf   = (float*)(ws + 167772160ull);         // 1 MB
  float* kbias= (float*)(ws + 168820736ull);         // 32 KB

  cvt_kernel<<<16384, 256, 0, stream>>>(x, xb, 4194304);
  cvt_kernel<<<12288, 256, 0, stream>>>(wqkv, wqkvb, 3145728);
  cvt_kernel<<<4096, 256, 0, stream>>>(wo, wob, 1048576);
  rope_kernel<<<1024, 256, 0, stream>>>(rf);
  bias_kernel<<<32, 256, 0, stream>>>(amask, kbias, Bb * Ss);

  gemm_qkv_kernel<<<dim3(48, 64), 256, 0, stream>>>(xb, wqkvb, rf, qb, kb, vtb);
  attn_kernel<<<dim3(2048), 256, 0, stream>>>(qb, kb, vtb, kbias, attn, xb /*obuf*/);
  gemm_out_kernel<<<dim3(16, 64), 256, 0, stream>>>(xb, wob, out);
}